// Round 4
// baseline (1075.732 us; speedup 1.0000x reference)
//
#include <hip/hip_runtime.h>

// 2-layer tanh RNN (B=4096, T=512, D=30) + MLP head (30->15->15->1), fp32.
//
// R12: R11's fused kernel was SPILLING (WRITE_SIZE 70MB vs 8MB out, FETCH
// +88MB over x: ~7-10 dwords scratch per step). Cause: waves_per_eu(4,4)
// caps the unified reg file at 128/wave while the fused live set (60 pinned
// weights + xv[30] projection + 15 pinned bpermute addrs) needs ~140-150.
// Measured occupancy was ~3 waves/SIMD anyway, so the cap bought nothing.
// Fix: waves_per_eu(3) (170-reg budget, no memory spills, same achieved
// occupancy) + un-PIN addr2 so LLVM can fold the +4k into the ds_bpermute
// offset immediate (frees up to 14 VGPRs).
//
// Structure (from R10/R11): single kernel, one wave per chain. Per pass
// (8 x 64 timesteps): stage 64 x-rows coalesced into LDS (pad-31), lane l
// projects row l in place (Wih1 from SGPRs, bit-identical to old kernel A),
// then 64 recurrence+head steps read xv from LDS.
// Carried from R9: head pipelined one step behind; phase 3 fused into
// phase 2 via ds_bpermute (lanes 16..30 pull v1_{t-1}, others h2); batched
// readlane->SGPR phases with sched_barrier to kill SGPR hazards.

namespace {
constexpr int T = 512;
constexpr int D = 30;   // hidden size
constexpr int H = 15;   // head hidden size
constexpr int PASS = 64;            // rows (timesteps) per LDS pass
constexpr int NPASS = T / PASS;     // 8

// tanh(x) = 1 - 2/(exp(2x)+1): NaN-free at +/-inf, ~1e-6 abs err.
__device__ __forceinline__ float fast_tanh(float x) {
  float e = __expf(2.0f * x);
  return 1.0f - 2.0f * __builtin_amdgcn_rcpf(e + 1.0f);
}

// Broadcast lane `lane`'s value (SGPR result, scalar operand of v_fma).
__device__ __forceinline__ float bcast(float v, int lane) {
  return __int_as_float(__builtin_amdgcn_readlane(__float_as_int(v), lane));
}

// Per-lane gather: pull lane (byteaddr>>2)'s value of v (VGPR result, DS pipe).
__device__ __forceinline__ float lanepull(float v, int byteaddr) {
  return __int_as_float(
      __builtin_amdgcn_ds_bpermute(byteaddr, __float_as_int(v)));
}

// Non-volatile pre-loop pin: value must materialize in a register here.
#define PIN(v) asm("" : "+v"(v))
}  // namespace

// ---------------------------------------------------------------------------
// Fused kernel: one wave per chain, 4096 blocks.
//  per pass p (8 passes of 64 timesteps):
//   stage:   64 x-rows -> LDS tile xs[64][31] (coalesced float2, pad 31)
//   project: lane l computes xw row l in place (Wih1 from SGPRs)
//   steps:   64 recurrence+head steps, xv from LDS (conflict-free: word
//            addr = tl*31 + r -> bank (r - tl) mod 32 distinct across lanes;
//            upper half reads same addr as lower -> broadcast, free)
// ---------------------------------------------------------------------------
__global__ __attribute__((amdgpu_waves_per_eu(3)))
__launch_bounds__(64) void rnn_fused2(
    const float* __restrict__ x,
    const float* __restrict__ Wih1, const float* __restrict__ Whh1,
    const float* __restrict__ bih1, const float* __restrict__ bhh1,
    const float* __restrict__ Wih2, const float* __restrict__ Whh2,
    const float* __restrict__ bih2, const float* __restrict__ bhh2,
    const float* __restrict__ W1, const float* __restrict__ b1,
    const float* __restrict__ W2, const float* __restrict__ b2,
    const float* __restrict__ W3, const float* __restrict__ b3,
    float* __restrict__ out) {
  __shared__ float xs[PASS * 31];      // 7936 B
  const int j = threadIdx.x;           // 0..63
  const bool lo = (j < 32);
  const int ju = j & 31;
  const int r = (ju < D) ? ju : (D - 1);  // clamped row index 0..29

  // ---- per-lane weight rows (60 total) ----
  float aw[D], bw[D];
  {
    const float* Ar = (lo ? Whh1 : Wih2) + r * D;
#pragma unroll
    for (int k = 0; k < D; ++k) aw[k] = Ar[k];
#pragma unroll
    for (int k = 0; k < D; ++k) {
      float v;
      if (!lo)
        v = Whh2[r * D + k];
      else if (j < H)
        v = W1[j * D + k];                 // lanes 0..14: W1 rows (-> v1)
      else if (j >= 16 && j < 31 && k < H)
        v = W2[(j - 16) * H + k];          // lanes 16..30: W2 rows (-> v2)
      else
        v = 0.0f;                          // lanes 15, 31: dead
      bw[k] = v;
    }
  }
#pragma unroll
  for (int k = 0; k < D; ++k) {
    PIN(aw[k]);
    PIN(bw[k]);
  }

  // phase-2 ds_bpermute base byte address:
  //  consumer lanes 16..31 pull lane k    (v1_{t-1} slot of g)  -> base 0
  //  all other lanes      pull lane 32+k (h2_t slot of g)       -> base 128
  // addr for k is abase + 4k; un-pinned so LLVM may fold 4k into the DS
  // offset immediate (saves up to 14 VGPRs vs the pinned-array version).
  const int abase = (j >= 16 && j < 32) ? 0 : 128;

  // biasA2m: layer-2 bias on upper lanes, 0 on lower (so rec1 stays pure).
  float biasA2m = lo ? 0.0f : (bih2[r] + bhh2[r]);
  // biasB: lanes 0..14 = b1, lanes 16..30 = b2, else 0 (keeps rec2 pure).
  float biasB = (j < H) ? b1[j] : ((j >= 16 && j < 31) ? b2[j - 16] : 0.0f);
  // w3v is 0 outside lanes 16..30; dead-lane tv is finite -> plain mul is safe.
  float w3v = (j >= 16 && j < 31) ? W3[j - 16] : 0.0f;
  const float sb3 = b3[0];
  PIN(biasA2m);
  PIN(biasB);
  PIN(w3v);

  const float* xrow = x + (long)blockIdx.x * (T * D);
  float* outp = out + (long)blockIdx.x * T;
  const int cj = r;  // per-lane xw slot (clamped; upper lanes mirror lower)

  float rec1 = 0.0f;  // Whh1*h1_{t-1}, valid on lower lanes
  float rec2 = 0.0f;  // Whh2*h2_{t-1}, valid on upper lanes
  float v1p = 0.0f;   // v1_{t-1}, valid on lanes 0..14 (0 before t=0)

  auto step = [&](float xv) -> float {
    // xv holds Wih1.x_t + bih1 + bhh1 (from the LDS-projected tile)
    const float h1 = fast_tanh(xv + rec1);  // valid on lanes 0..29

    // ---- phase 1: broadcast h1; lower->rec1_next, upper->layer2 preact ----
    float s1[D];
#pragma unroll
    for (int k = 0; k < D; ++k) s1[k] = bcast(h1, k);
    __builtin_amdgcn_sched_barrier(0);
    float p0 = biasA2m, p1 = 0.0f, p2 = 0.0f, p3 = 0.0f;  // 0 on lower
#pragma unroll
    for (int k = 0; k < D; ++k) {
      if ((k & 3) == 0)
        p0 = fmaf(aw[k], s1[k], p0);
      else if ((k & 3) == 1)
        p1 = fmaf(aw[k], s1[k], p1);
      else if ((k & 3) == 2)
        p2 = fmaf(aw[k], s1[k], p2);
      else
        p3 = fmaf(aw[k], s1[k], p3);
    }
    const float P1 = (p0 + p1) + (p2 + p3);
    rec1 = P1;                                // meaningful on lower (pure dot)
    const float h2 = fast_tanh(P1 + rec2);    // valid on lanes 32..61

    // ---- phase 2 (fused head): per-lane broadcast source ----
    const float g = (j < 16) ? v1p : h2;  // src lanes 0..14: v1p; 32..61: h2
    float bb[H];
#pragma unroll
    for (int k = 0; k < H; ++k) bb[k] = lanepull(g, abase + 4 * k);  // DS pipe
    float sh[D - H];
#pragma unroll
    for (int k = H; k < D; ++k) sh[k - H] = bcast(h2, 32 + k);  // VALU->SGPR
    __builtin_amdgcn_sched_barrier(0);
    float q0 = biasB, q1 = 0.0f, q2 = 0.0f, q3 = 0.0f;  // biasB==0 on upper
#pragma unroll
    for (int k = 0; k < D; ++k) {
      const float s = (k < H) ? bb[k] : sh[k - H];
      if ((k & 3) == 0)
        q0 = fmaf(bw[k], s, q0);
      else if ((k & 3) == 1)
        q1 = fmaf(bw[k], s, q1);
      else if ((k & 3) == 2)
        q2 = fmaf(bw[k], s, q2);
      else
        q3 = fmaf(bw[k], s, q3);
    }
    const float P2 = (q0 + q1) + (q2 + q3);
    rec2 = P2;                       // meaningful on upper (pure dot)
    const float tv = fast_tanh(P2);  // v1_t on lanes 0..14, v2_{t-1} on 16..30
    v1p = tv;

    // ---- head layer 3: reduce W3.v2_{t-1} within group [16,31] ----
    float pv = w3v * tv;  // w3v==0 kills non-mid lanes (tv finite there)
    pv += __shfl_xor(pv, 8, 16);
    pv += __shfl_xor(pv, 4, 16);
    pv += __shfl_xor(pv, 2, 16);
    pv += __shfl_xor(pv, 1, 16);
    return pv;  // out[t-1] (pre-b3), valid on lanes 16..31
  };

  float carry = 0.0f;  // out[t] value awaiting its even-aligned pair store
#pragma unroll 1
  for (int p = 0; p < NPASS; ++p) {
    // ---- stage: 64 rows (PASS*D = 1920 floats) coalesced into LDS ----
    const float* src = xrow + p * (PASS * D);
#pragma unroll
    for (int it = 0; it < 15; ++it) {
      const int idx = it * 128 + j * 2;      // even -> col even, col+1 same row
      const float2 v = *(const float2*)(src + idx);
      const int row = idx / 30;              // magic-mul
      const int col = idx - row * 30;
      xs[row * 31 + col] = v.x;
      xs[row * 31 + col + 1] = v.y;
    }
    __syncthreads();  // 1 wave: ~free; drains lgkmcnt, cross-lane visibility

    // ---- project: lane j owns row j; in-place xw = Wih1.x + (bih1+bhh1) ----
    {
      float xv[D];
#pragma unroll
      for (int k = 0; k < D; ++k) xv[k] = xs[j * 31 + k];
      __syncthreads();  // reads done before in-place overwrite
#pragma unroll
      for (int i = 0; i < D; ++i) {
        float a = bih1[i] + bhh1[i];         // uniform -> s_load
#pragma unroll
        for (int k = 0; k < D; ++k) a = fmaf(Wih1[i * D + k], xv[k], a);
        xs[j * 31 + i] = a;                  // own-row writeback (no race)
      }
    }
    __syncthreads();

    // ---- 64 recurrence steps (32 A/B pairs) ----
#pragma unroll 1
    for (int tl = 0; tl < PASS; tl += 2) {
      const int t = p * PASS + tl;
      const float xvA = xs[tl * 31 + cj];
      const float xvB = xs[(tl + 1) * 31 + cj];
      const float pA = step(xvA);            // out[t-1]
      if ((p | tl) && j == 16) {
        float2 o;
        o.x = carry + sb3;  // out[t-2]
        o.y = pA + sb3;     // out[t-1]
        *(float2*)(outp + (t - 2)) = o;      // even offset -> 8B aligned
      }
      carry = step(xvB);                     // out[t]
    }
    __syncthreads();  // this pass's reads done before next pass's staging
  }

  // ---- epilogue: head-only pass for out[T-1] from v1_{T-1} ----
  {
    float bb[H];
#pragma unroll
    for (int k = 0; k < H; ++k) bb[k] = lanepull(v1p, abase + 4 * k);
    float u0 = biasB, u1 = 0.0f, u2 = 0.0f, u3 = 0.0f;
#pragma unroll
    for (int k = 0; k < H; ++k) {
      if ((k & 3) == 0)
        u0 = fmaf(bw[k], bb[k], u0);
      else if ((k & 3) == 1)
        u1 = fmaf(bw[k], bb[k], u1);
      else if ((k & 3) == 2)
        u2 = fmaf(bw[k], bb[k], u2);
      else
        u3 = fmaf(bw[k], bb[k], u3);
    }
    const float v2 = fast_tanh((u0 + u1) + (u2 + u3));  // lanes 16..30
    float pv = w3v * v2;
    pv += __shfl_xor(pv, 8, 16);
    pv += __shfl_xor(pv, 4, 16);
    pv += __shfl_xor(pv, 2, 16);
    pv += __shfl_xor(pv, 1, 16);
    if (j == 16) {
      float2 o;
      o.x = carry + sb3;  // out[T-2]
      o.y = pv + sb3;     // out[T-1]
      *(float2*)(outp + (T - 2)) = o;
    }
  }
}

extern "C" void kernel_launch(void* const* d_in, const int* in_sizes, int n_in,
                              void* d_out, int out_size, void* d_ws,
                              size_t ws_size, hipStream_t stream) {
  const float* x = (const float*)d_in[0];
  const float* Wih1 = (const float*)d_in[1];
  const float* Whh1 = (const float*)d_in[2];
  const float* bih1 = (const float*)d_in[3];
  const float* bhh1 = (const float*)d_in[4];
  const float* Wih2 = (const float*)d_in[5];
  const float* Whh2 = (const float*)d_in[6];
  const float* bih2 = (const float*)d_in[7];
  const float* bhh2 = (const float*)d_in[8];
  const float* W1 = (const float*)d_in[9];
  const float* b1 = (const float*)d_in[10];
  const float* W2 = (const float*)d_in[11];
  const float* b2 = (const float*)d_in[12];
  const float* W3 = (const float*)d_in[13];
  const float* b3 = (const float*)d_in[14];

  const int B = in_sizes[0] / (T * D);  // 4096 chains
  (void)d_ws;
  (void)ws_size;

  hipLaunchKernelGGL(rnn_fused2, dim3(B), dim3(64), 0, stream, x, Wih1, Whh1,
                     bih1, bhh1, Wih2, Whh2, bih2, bhh2, W1, b1, W2, b2, W3,
                     b3, (float*)d_out);
}

// Round 6
// 889.410 us; speedup vs baseline: 1.2095x; 1.2095x over previous
//
#include <hip/hip_runtime.h>

// 2-layer tanh RNN (B=4096, T=512, D=30) + MLP head (30->15->15->1), fp32.
//
// R14 = R13 verbatim resubmit (R13 died in container infra, no counters;
// same pattern as R10->R11 which ran fine on resubmit; audit found no
// fault/hang path: bounds, arg order, trip counts all static and in-range).
//
// R13 theory: combine the proven halves of R3/R4. R3 ((4,4) pin, pinned
// addr2): occupancy 38%, 62MB spills, 778us. R4 (no pin, unpinned addr2):
// spills 19MB but occupancy 27%, 875us. This round: (4,4) pin restored
// (guarantees the one-batch 16 waves/CU residency for all 4096 chains) +
// unpinned addr2 (ds_bpermute offset-immediate folding, ~14 fewer live
// VGPRs) + transient live-range caps (#pragma unroll 5 staging, unroll 3
// projection: bounds in-flight loads and the hoisted-weights SGPR window)
// + distance-1-pair LDS prefetch of xvA/xvB (kills the ~120cyc lgkm stall
// per pair).
//
// Structure (R10+): single kernel, one wave per chain. Per pass (8 x 64
// timesteps): stage 64 x-rows coalesced into LDS (pad-31), lane l projects
// row l in place (Wih1 via s_loads, bit-identical to old kernel A), then 64
// recurrence+head steps read xv from LDS.
// Carried from R9: head pipelined one step behind; phase 3 fused into
// phase 2 via ds_bpermute (lanes 16..30 pull v1_{t-1}, others h2); batched
// readlane->SGPR phases with sched_barrier to kill SGPR hazards.

namespace {
constexpr int T = 512;
constexpr int D = 30;   // hidden size
constexpr int H = 15;   // head hidden size
constexpr int PASS = 64;            // rows (timesteps) per LDS pass
constexpr int NPASS = T / PASS;     // 8

// tanh(x) = 1 - 2/(exp(2x)+1): NaN-free at +/-inf, ~1e-6 abs err.
__device__ __forceinline__ float fast_tanh(float x) {
  float e = __expf(2.0f * x);
  return 1.0f - 2.0f * __builtin_amdgcn_rcpf(e + 1.0f);
}

// Broadcast lane `lane`'s value (SGPR result, scalar operand of v_fma).
__device__ __forceinline__ float bcast(float v, int lane) {
  return __int_as_float(__builtin_amdgcn_readlane(__float_as_int(v), lane));
}

// Per-lane gather: pull lane (byteaddr>>2)'s value of v (VGPR result, DS pipe).
__device__ __forceinline__ float lanepull(float v, int byteaddr) {
  return __int_as_float(
      __builtin_amdgcn_ds_bpermute(byteaddr, __float_as_int(v)));
}

// Non-volatile pre-loop pin: value must materialize in a register here.
#define PIN(v) asm("" : "+v"(v))
}  // namespace

// ---------------------------------------------------------------------------
// Fused kernel: one wave per chain, 4096 blocks (= 16 waves/CU, one batch
// under the (4,4) pin; LDS 8KB x 16 = 128KB < 160KB; slots 16 < 32).
//  per pass p (8 passes of 64 timesteps):
//   stage:   64 x-rows -> LDS tile xs[64][31] (coalesced float2, pad 31)
//   project: lane l computes xw row l in place (Wih1 via s_loads)
//   steps:   64 recurrence+head steps, xv from LDS (conflict-free: word
//            addr = tl*31 + r -> bank (r - tl) mod 32 distinct across lanes;
//            upper half reads same addr as lower -> broadcast, free)
// ---------------------------------------------------------------------------
__global__ __attribute__((amdgpu_waves_per_eu(4, 4)))
__launch_bounds__(64) void rnn_fused2(
    const float* __restrict__ x,
    const float* __restrict__ Wih1, const float* __restrict__ Whh1,
    const float* __restrict__ Wih2, const float* __restrict__ Whh2,
    const float* __restrict__ bih1, const float* __restrict__ bhh1,
    const float* __restrict__ bih2, const float* __restrict__ bhh2,
    const float* __restrict__ W1, const float* __restrict__ b1,
    const float* __restrict__ W2, const float* __restrict__ b2,
    const float* __restrict__ W3, const float* __restrict__ b3,
    float* __restrict__ out) {
  __shared__ float xs[PASS * 31];      // 7936 B
  const int j = threadIdx.x;           // 0..63
  const bool lo = (j < 32);
  const int ju = j & 31;
  const int r = (ju < D) ? ju : (D - 1);  // clamped row index 0..29

  // ---- per-lane weight rows (60 total) ----
  float aw[D], bw[D];
  {
    const float* Ar = (lo ? Whh1 : Wih2) + r * D;
#pragma unroll
    for (int k = 0; k < D; ++k) aw[k] = Ar[k];
#pragma unroll
    for (int k = 0; k < D; ++k) {
      float v;
      if (!lo)
        v = Whh2[r * D + k];
      else if (j < H)
        v = W1[j * D + k];                 // lanes 0..14: W1 rows (-> v1)
      else if (j >= 16 && j < 31 && k < H)
        v = W2[(j - 16) * H + k];          // lanes 16..30: W2 rows (-> v2)
      else
        v = 0.0f;                          // lanes 15, 31: dead
      bw[k] = v;
    }
  }
#pragma unroll
  for (int k = 0; k < D; ++k) {
    PIN(aw[k]);
    PIN(bw[k]);
  }

  // phase-2 ds_bpermute base byte address (un-pinned: LLVM folds the +4k
  // into the DS offset immediate; one live VGPR instead of 15):
  //  consumer lanes 16..31 pull lane k    (v1_{t-1} slot of g)  -> base 0
  //  all other lanes      pull lane 32+k (h2_t slot of g)       -> base 128
  const int abase = (j >= 16 && j < 32) ? 0 : 128;

  // biasA2m: layer-2 bias on upper lanes, 0 on lower (so rec1 stays pure).
  float biasA2m = lo ? 0.0f : (bih2[r] + bhh2[r]);
  // biasB: lanes 0..14 = b1, lanes 16..30 = b2, else 0 (keeps rec2 pure).
  float biasB = (j < H) ? b1[j] : ((j >= 16 && j < 31) ? b2[j - 16] : 0.0f);
  // w3v is 0 outside lanes 16..30; dead-lane tv is finite -> plain mul is safe.
  float w3v = (j >= 16 && j < 31) ? W3[j - 16] : 0.0f;
  const float sb3 = b3[0];
  PIN(biasA2m);
  PIN(biasB);
  PIN(w3v);

  const float* xrow = x + (long)blockIdx.x * (T * D);
  float* outp = out + (long)blockIdx.x * T;
  const int cj = r;  // per-lane xw slot (clamped; upper lanes mirror lower)

  float rec1 = 0.0f;  // Whh1*h1_{t-1}, valid on lower lanes
  float rec2 = 0.0f;  // Whh2*h2_{t-1}, valid on upper lanes
  float v1p = 0.0f;   // v1_{t-1}, valid on lanes 0..14 (0 before t=0)

  auto step = [&](float xv) -> float {
    // xv holds Wih1.x_t + bih1 + bhh1 (from the LDS-projected tile)
    const float h1 = fast_tanh(xv + rec1);  // valid on lanes 0..29

    // ---- phase 1: broadcast h1; lower->rec1_next, upper->layer2 preact ----
    float s1[D];
#pragma unroll
    for (int k = 0; k < D; ++k) s1[k] = bcast(h1, k);
    __builtin_amdgcn_sched_barrier(0);
    float p0 = biasA2m, p1 = 0.0f, p2 = 0.0f, p3 = 0.0f;  // 0 on lower
#pragma unroll
    for (int k = 0; k < D; ++k) {
      if ((k & 3) == 0)
        p0 = fmaf(aw[k], s1[k], p0);
      else if ((k & 3) == 1)
        p1 = fmaf(aw[k], s1[k], p1);
      else if ((k & 3) == 2)
        p2 = fmaf(aw[k], s1[k], p2);
      else
        p3 = fmaf(aw[k], s1[k], p3);
    }
    const float P1 = (p0 + p1) + (p2 + p3);
    rec1 = P1;                                // meaningful on lower (pure dot)
    const float h2 = fast_tanh(P1 + rec2);    // valid on lanes 32..61

    // ---- phase 2 (fused head): per-lane broadcast source ----
    const float g = (j < 16) ? v1p : h2;  // src lanes 0..14: v1p; 32..61: h2
    float bb[H];
#pragma unroll
    for (int k = 0; k < H; ++k) bb[k] = lanepull(g, abase + 4 * k);  // DS pipe
    float sh[D - H];
#pragma unroll
    for (int k = H; k < D; ++k) sh[k - H] = bcast(h2, 32 + k);  // VALU->SGPR
    __builtin_amdgcn_sched_barrier(0);
    float q0 = biasB, q1 = 0.0f, q2 = 0.0f, q3 = 0.0f;  // biasB==0 on upper
#pragma unroll
    for (int k = 0; k < D; ++k) {
      const float s = (k < H) ? bb[k] : sh[k - H];
      if ((k & 3) == 0)
        q0 = fmaf(bw[k], s, q0);
      else if ((k & 3) == 1)
        q1 = fmaf(bw[k], s, q1);
      else if ((k & 3) == 2)
        q2 = fmaf(bw[k], s, q2);
      else
        q3 = fmaf(bw[k], s, q3);
    }
    const float P2 = (q0 + q1) + (q2 + q3);
    rec2 = P2;                       // meaningful on upper (pure dot)
    const float tv = fast_tanh(P2);  // v1_t on lanes 0..14, v2_{t-1} on 16..30
    v1p = tv;

    // ---- head layer 3: reduce W3.v2_{t-1} within group [16,31] ----
    float pv = w3v * tv;  // w3v==0 kills non-mid lanes (tv finite there)
    pv += __shfl_xor(pv, 8, 16);
    pv += __shfl_xor(pv, 4, 16);
    pv += __shfl_xor(pv, 2, 16);
    pv += __shfl_xor(pv, 1, 16);
    return pv;  // out[t-1] (pre-b3), valid on lanes 16..31
  };

  float carry = 0.0f;  // out[t] value awaiting its even-aligned pair store
#pragma unroll 1
  for (int p = 0; p < NPASS; ++p) {
    // ---- stage: 64 rows (PASS*D = 1920 floats) coalesced into LDS ----
    // unroll 5: caps in-flight load registers at 10 dwords (3 batches);
    // idle-wait between batches is absorbed by the other 15 waves/CU.
    const float* src = xrow + p * (PASS * D);
#pragma unroll 5
    for (int it = 0; it < 15; ++it) {
      const int idx = it * 128 + j * 2;      // even -> col even, col+1 same row
      const float2 v = *(const float2*)(src + idx);
      const int row = idx / 30;              // magic-mul
      const int col = idx - row * 30;
      xs[row * 31 + col] = v.x;
      xs[row * 31 + col + 1] = v.y;
    }
    __syncthreads();  // 1 wave: ~free; drains cnts, cross-lane visibility

    // ---- project: lane j owns row j; in-place xw = Wih1.x + (bih1+bhh1) ----
    {
      float xv[D];
#pragma unroll
      for (int k = 0; k < D; ++k) xv[k] = xs[j * 31 + k];
      __syncthreads();  // reads done before in-place overwrite
      // unroll 3: caps the hoisted Wih1 s_load window at 90 scalars
      // (bounds SGPR pressure; SGPR spills hit scratch under the 128 cap).
#pragma unroll 3
      for (int i = 0; i < D; ++i) {
        float a = bih1[i] + bhh1[i];         // uniform -> s_load
#pragma unroll
        for (int k = 0; k < D; ++k) a = fmaf(Wih1[i * D + k], xv[k], a);
        xs[j * 31 + i] = a;                  // own-row writeback (no race)
      }
    }
    __syncthreads();

    // ---- 64 recurrence steps (32 A/B pairs), distance-1-pair prefetch ----
    float xvA = xs[cj];           // pair 0
    float xvB = xs[31 + cj];
#pragma unroll 1
    for (int tl = 0; tl < PASS; tl += 2) {
      const int t = p * PASS + tl;
      const int tn = (tl + 2) & (PASS - 1);  // next pair (wraps to dummy 0)
      const float nA = xs[tn * 31 + cj];     // issued ~1000cyc before use
      const float nB = xs[(tn + 1) * 31 + cj];
      const float pA = step(xvA);            // out[t-1]
      if ((p | tl) && j == 16) {
        float2 o;
        o.x = carry + sb3;  // out[t-2]
        o.y = pA + sb3;     // out[t-1]
        *(float2*)(outp + (t - 2)) = o;      // even offset -> 8B aligned
      }
      carry = step(xvB);                     // out[t]
      xvA = nA;
      xvB = nB;
    }
    __syncthreads();  // this pass's reads done before next pass's staging
  }

  // ---- epilogue: head-only pass for out[T-1] from v1_{T-1} ----
  {
    float bb[H];
#pragma unroll
    for (int k = 0; k < H; ++k) bb[k] = lanepull(v1p, abase + 4 * k);
    float u0 = biasB, u1 = 0.0f, u2 = 0.0f, u3 = 0.0f;
#pragma unroll
    for (int k = 0; k < H; ++k) {
      if ((k & 3) == 0)
        u0 = fmaf(bw[k], bb[k], u0);
      else if ((k & 3) == 1)
        u1 = fmaf(bw[k], bb[k], u1);
      else if ((k & 3) == 2)
        u2 = fmaf(bw[k], bb[k], u2);
      else
        u3 = fmaf(bw[k], bb[k], u3);
    }
    const float v2 = fast_tanh((u0 + u1) + (u2 + u3));  // lanes 16..30
    float pv = w3v * v2;
    pv += __shfl_xor(pv, 8, 16);
    pv += __shfl_xor(pv, 4, 16);
    pv += __shfl_xor(pv, 2, 16);
    pv += __shfl_xor(pv, 1, 16);
    if (j == 16) {
      float2 o;
      o.x = carry + sb3;  // out[T-2]
      o.y = pv + sb3;     // out[T-1]
      *(float2*)(outp + (T - 2)) = o;
    }
  }
}

extern "C" void kernel_launch(void* const* d_in, const int* in_sizes, int n_in,
                              void* d_out, int out_size, void* d_ws,
                              size_t ws_size, hipStream_t stream) {
  const float* x = (const float*)d_in[0];
  const float* Wih1 = (const float*)d_in[1];
  const float* Whh1 = (const float*)d_in[2];
  const float* bih1 = (const float*)d_in[3];
  const float* bhh1 = (const float*)d_in[4];
  const float* Wih2 = (const float*)d_in[5];
  const float* Whh2 = (const float*)d_in[6];
  const float* bih2 = (const float*)d_in[7];
  const float* bhh2 = (const float*)d_in[8];
  const float* W1 = (const float*)d_in[9];
  const float* b1 = (const float*)d_in[10];
  const float* W2 = (const float*)d_in[11];
  const float* b2 = (const float*)d_in[12];
  const float* W3 = (const float*)d_in[13];
  const float* b3 = (const float*)d_in[14];

  const int B = in_sizes[0] / (T * D);  // 4096 chains
  (void)d_ws;
  (void)ws_size;

  hipLaunchKernelGGL(rnn_fused2, dim3(B), dim3(64), 0, stream, x, Wih1, Whh1,
                     Wih2, Whh2, bih1, bhh1, bih2, bhh2, W1, b1, W2, b2, W3,
                     b3, (float*)d_out);
}